// Round 1
// baseline (571.141 us; speedup 1.0000x reference)
//
#include <hip/hip_runtime.h>
#include <math.h>

// LIF over T=4 steps, elementwise over B*N. T is innermost & contiguous,
// so each thread processes one (b,n): float4 in from x, float4 from lateral,
// 4-step recurrence in registers, float4 out. Pure HBM-bandwidth-bound:
// 768 MiB traffic -> ~128 us floor at 6.3 TB/s.

#define TAU 0.25f

__global__ __launch_bounds__(256) void lif_kernel(
    const float4* __restrict__ x,
    const float4* __restrict__ lat,
    const float* __restrict__ w,
    float4* __restrict__ out,
    int n4)
{
    int i = blockIdx.x * blockDim.x + threadIdx.x;
    if (i >= n4) return;

    const float thre = tanhf(*w);

    float4 xv = x[i];
    float4 lv = lat[i];

    float xa[4] = {xv.x, xv.y, xv.z, xv.w};
    float la[4] = {lv.x, lv.y, lv.z, lv.w};
    float oa[4];

    float u = 0.0f;
    float o = 0.0f;
#pragma unroll
    for (int t = 0; t < 4; ++t) {
        // reset = 1 - (o_prev > thre)
        float reset = (o > thre) ? 0.0f : 1.0f;
        u = TAU * u * reset + xa[t] + la[t];
        // spike forward: o = u if u > thre else 0
        o = (u > thre) ? u : 0.0f;
        oa[t] = o;
    }

    out[i] = make_float4(oa[0], oa[1], oa[2], oa[3]);
}

extern "C" void kernel_launch(void* const* d_in, const int* in_sizes, int n_in,
                              void* d_out, int out_size, void* d_ws, size_t ws_size,
                              hipStream_t stream)
{
    const float* x   = (const float*)d_in[0];
    const float* lat = (const float*)d_in[1];
    const float* w   = (const float*)d_in[2];
    float* out       = (float*)d_out;

    int n4 = in_sizes[0] / 4;  // number of (b,n) groups; T=4 packed per float4

    const int block = 256;
    const int grid = (n4 + block - 1) / block;
    lif_kernel<<<grid, block, 0, stream>>>(
        (const float4*)x, (const float4*)lat, w, (float4*)out, n4);
}

// Round 2
// 558.827 us; speedup vs baseline: 1.0220x; 1.0220x over previous
//
#include <hip/hip_runtime.h>
#include <math.h>

// LIF over T=4 steps, elementwise over B*N. T innermost & contiguous:
// one float4 from x + one from lateral per (b,n) group, 4-step recurrence
// in registers, one float4 out. Pure streaming, zero reuse ->
// nontemporal loads/stores + 4 groups/thread for deep MLP.
// Logical traffic 768 MiB; 6.3 TB/s ceiling -> ~122 us kernel floor.

#define TAU 0.25f
#define ITEMS 4
#define BLOCK 256

typedef float v4f __attribute__((ext_vector_type(4)));

__global__ __launch_bounds__(BLOCK) void lif_kernel(
    const v4f* __restrict__ x,
    const v4f* __restrict__ lat,
    const float* __restrict__ w,
    v4f* __restrict__ out,
    int n4)
{
    const float thre = tanhf(*w);

    // Block tile of BLOCK*ITEMS float4 groups; thread t handles
    // tile_base + t + k*BLOCK (coalesced within each k).
    int base = blockIdx.x * (BLOCK * ITEMS) + threadIdx.x;

    v4f xv[ITEMS], lv[ITEMS];
#pragma unroll
    for (int k = 0; k < ITEMS; ++k) {
        int idx = base + k * BLOCK;
        if (idx < n4) {
            xv[k] = __builtin_nontemporal_load(&x[idx]);
            lv[k] = __builtin_nontemporal_load(&lat[idx]);
        }
    }

#pragma unroll
    for (int k = 0; k < ITEMS; ++k) {
        int idx = base + k * BLOCK;
        if (idx >= n4) continue;
        float u = 0.0f;
        float o = 0.0f;
        v4f ov;
#pragma unroll
        for (int t = 0; t < 4; ++t) {
            // reset = 1 - (o_prev > thre)
            float reset = (o > thre) ? 0.0f : 1.0f;
            u = TAU * u * reset + xv[k][t] + lv[k][t];
            // spike forward: o = u if u > thre else 0
            o = (u > thre) ? u : 0.0f;
            ov[t] = o;
        }
        __builtin_nontemporal_store(ov, &out[idx]);
    }
}

extern "C" void kernel_launch(void* const* d_in, const int* in_sizes, int n_in,
                              void* d_out, int out_size, void* d_ws, size_t ws_size,
                              hipStream_t stream)
{
    const float* x   = (const float*)d_in[0];
    const float* lat = (const float*)d_in[1];
    const float* w   = (const float*)d_in[2];
    float* out       = (float*)d_out;

    int n4 = in_sizes[0] / 4;  // (b,n) groups; T=4 packed per float4

    int groups_per_block = BLOCK * ITEMS;
    int grid = (n4 + groups_per_block - 1) / groups_per_block;
    lif_kernel<<<grid, BLOCK, 0, stream>>>(
        (const v4f*)x, (const v4f*)lat, w, (v4f*)out, n4);
}